// Round 9
// baseline (200.602 us; speedup 1.0000x reference)
//
#include <hip/hip_runtime.h>

typedef unsigned int   u32;
typedef unsigned short u16;
typedef short bf16x8 __attribute__((ext_vector_type(8)));
typedef float f32x4  __attribute__((ext_vector_type(4)));

#define GAS(p) ((const __attribute__((address_space(1))) void*)(p))
#define LAS(p) ((__attribute__((address_space(3))) void*)(p))

__device__ __forceinline__ u16 f2bf(float f) {
  union { float f; u32 u; } v; v.f = f;
  u32 r = v.u + 0x7fffu + ((v.u >> 16) & 1u);
  return (u16)(r >> 16);
}
__device__ __forceinline__ u32 pack2(float a, float b) {
  return (u32)f2bf(a) | ((u32)f2bf(b) << 16);
}

#define EPI_QK_SPLIT_BF16 0
#define EPI_BIAS_ROW_BF16 1
#define EPI_SCALE_F32     2
#define EPI_BIAS_COL_F32  3
#define EPI_RESHAPE_BF16  4

// ---------------- unified f32 -> bf16 convert (all 5 inputs, 1 launch) -------
__global__ __launch_bounds__(256) void cvt_all(
    const float* __restrict__ q,  const float* __restrict__ wq,
    const float* __restrict__ wk, const float* __restrict__ wv,
    const float* __restrict__ wo, u16* __restrict__ xb,
    u16* __restrict__ wqkb, u16* __restrict__ wvb, u16* __restrict__ wob) {
  const int b = blockIdx.x;
  const float* src; u16* dst; long off;
  if (b < 2048)      { src = q;  dst = xb;             off = (long)b * 2048; }
  else if (b < 2560) { src = wq; dst = wqkb;           off = (long)(b - 2048) * 2048; }
  else if (b < 3072) { src = wk; dst = wqkb + 1048576; off = (long)(b - 2560) * 2048; }
  else if (b < 3584) { src = wv; dst = wvb;            off = (long)(b - 3072) * 2048; }
  else               { src = wo; dst = wob;            off = (long)(b - 3584) * 2048; }
  const long i = off + (long)threadIdx.x * 8;
  const float4* xp = (const float4*)(src + i);
  float4 a = xp[0], c = xp[1];
  uint4 o;
  o.x = pack2(a.x, a.y); o.y = pack2(a.z, a.w);
  o.z = pack2(c.x, c.y); o.w = pack2(c.z, c.w);
  *(uint4*)(dst + i) = o;
}

// ========= 4-wave m97-geometry GEMM: 128x128 tile, acc[4][4], 1 buffer =======
// 64x64 wave-tile = 64 FLOP per LDS byte (1.5x better than 8-wave 64x32).
// Proven structure (m97: 874-912 TF at >=3 blocks/CU; m102 shape curve).
// Needs blocks/CU >= 2 for cross-block stall hiding - grids chosen accordingly.
// 32 KB LDS, ~164 VGPR -> 3 blocks/CU. XOR-swizzle per G4/rule 21.
template <int EPI>
__device__ __forceinline__
void gemm4_body(const u16* __restrict__ Ab, int lda,
                const u16* __restrict__ Bb, int ldb,
                void* __restrict__ Cv, void* __restrict__ Cv2, long coff, int ldc,
                const float* __restrict__ bias, const float* __restrict__ bias2,
                float scale, int kTiles, long tm, long tn,
                u16* As, u16* Bs) {
  const int tid = threadIdx.x, lane = tid & 63, w = tid >> 6;
  const int wm = w >> 1, wn = w & 1;      // wave grid 2x2
  const int rl = lane >> 3;               // row-in-stripe this lane stages
  const int sl = (lane & 7) ^ rl;         // pre-swizzled 16B-slot index
  const int fr = lane & 15, fq = lane >> 4;

  f32x4 acc[4][4] = {};

  for (int kt = 0; kt < kTiles; ++kt) {
    const int k0 = kt * 64;
#pragma unroll
    for (int i = 0; i < 4; ++i) {
      const u16* g = Ab + (tm + i * 32 + w * 8 + rl) * (long)lda + k0 + sl * 8;
      __builtin_amdgcn_global_load_lds(GAS(g), LAS(As + (i * 32 + w * 8) * 64), 16, 0, 0);
    }
#pragma unroll
    for (int i = 0; i < 4; ++i) {
      const u16* g = Bb + (tn + i * 32 + w * 8 + rl) * (long)ldb + k0 + sl * 8;
      __builtin_amdgcn_global_load_lds(GAS(g), LAS(Bs + (i * 32 + w * 8) * 64), 16, 0, 0);
    }
    __syncthreads();
#pragma unroll
    for (int ks = 0; ks < 2; ++ks) {
      bf16x8 af[4], bfr[4];
#pragma unroll
      for (int mt = 0; mt < 4; ++mt) {
        int row = wm * 64 + mt * 16 + fr;
        int slot = (ks * 4 + fq) ^ (row & 7);
        af[mt] = *(const bf16x8*)(As + row * 64 + slot * 8);
      }
#pragma unroll
      for (int nt = 0; nt < 4; ++nt) {
        int row = wn * 64 + nt * 16 + fr;
        int slot = (ks * 4 + fq) ^ (row & 7);
        bfr[nt] = *(const bf16x8*)(Bs + row * 64 + slot * 8);
      }
#pragma unroll
      for (int mt = 0; mt < 4; ++mt)
#pragma unroll
        for (int nt = 0; nt < 4; ++nt)
          acc[mt][nt] = __builtin_amdgcn_mfma_f32_16x16x32_bf16(af[mt], bfr[nt], acc[mt][nt], 0, 0, 0);
    }
    __syncthreads();
  }

  // epilogue: C/D layout col=lane&15, row=(lane>>4)*4+reg (verified m89/m91)
  const int cr = (lane >> 4) * 4;
  const int cc = lane & 15;
#pragma unroll
  for (int mt = 0; mt < 4; ++mt) {
#pragma unroll
    for (int nt = 0; nt < 4; ++nt) {
#pragma unroll
      for (int r = 0; r < 4; ++r) {
        float v = acc[mt][nt][r];
        long gm = tm + wm * 64 + mt * 16 + cr + r;
        long gn = tn + wn * 64 + nt * 16 + cc;
        if constexpr (EPI == EPI_QK_SPLIT_BF16) {
          if (gn < 1024) ((u16*)Cv )[gm * (long)ldc + gn]        = f2bf(v + bias [gn]);
          else           ((u16*)Cv2)[gm * (long)ldc + gn - 1024] = f2bf(v + bias2[gn - 1024]);
        } else if constexpr (EPI == EPI_BIAS_ROW_BF16) {
          ((u16*)Cv)[gm * (long)ldc + gn] = f2bf(v + bias[gm]);
        } else if constexpr (EPI == EPI_SCALE_F32) {
          ((float*)Cv)[coff + gm * ldc + gn] = v * scale;
        } else if constexpr (EPI == EPI_BIAS_COL_F32) {
          ((float*)Cv)[gm * (long)ldc + gn] = v + bias[gn];
        } else {  // EPI_RESHAPE_BF16
          long rr  = (gn >> 6) * 128 + (gm >> 4);
          long cc2 = ((gm & 15) << 6) + (gn & 63);
          ((u16*)Cv)[coff + rr * 1024 + cc2] = f2bf(v);
        }
      }
    }
  }
}

// QK-projection: [Q|K] = X@[Wq;Wk]^T + bias. 512 tiles = 2 blocks/CU.
__global__ __launch_bounds__(256, 3)
void k_qk(const u16* __restrict__ Xb, const u16* __restrict__ Wqkb,
          u16* __restrict__ Qb, u16* __restrict__ Kb,
          const float* __restrict__ bq, const float* __restrict__ bk) {
  __shared__ __align__(16) u16 As[8192], Bs[8192];  // 32 KiB
  const int b = blockIdx.x;
  const int job = (b & 7) * 64 + (b >> 3);          // XCD swizzle (512%8==0)
  long tm = (long)(job & 31) * 128, tn = (long)(job >> 5) * 128;
  gemm4_body<EPI_QK_SPLIT_BF16>(Xb, 1024, Wqkb, 1024, Qb, Kb, 0, 1024,
                                bq, bk, 0.f, 16, tm, tn, As, Bs);
}

// V-projection (jobs 0..255) + scores (jobs 256..767). 768 tiles = 3 blocks/CU.
__global__ __launch_bounds__(256, 3)
void k_vsc(const u16* __restrict__ Xb, const u16* __restrict__ Wvb,
           const u16* __restrict__ Qb, const u16* __restrict__ Kb,
           u16* __restrict__ Vtb, float* __restrict__ Sc,
           const float* __restrict__ bv) {
  __shared__ __align__(16) u16 As[8192], Bs[8192];
  const int b = blockIdx.x;
  const int job = (b & 7) * 96 + (b >> 3);          // XCD swizzle (768%8==0)
  if (job < 256) {  // Vt = Wv@X^T + bv[row]  (M=1024,N=4096,K=1024)
    long tm = (long)(job & 7) * 128, tn = (long)(job >> 3) * 128;
    gemm4_body<EPI_BIAS_ROW_BF16>(Wvb, 1024, Xb, 1024, Vtb, nullptr, 0, 4096,
                                  bv, nullptr, 0.f, 16, tm, tn, As, Bs);
  } else {          // scores = (Q@K^T)/128 per batch (M=2048,N=2048,K=1024)
    const int s = job - 256;
    const int z = s >> 8, r = s & 255;
    long tm = (long)(r & 15) * 128, tn = (long)(r >> 4) * 128;
    gemm4_body<EPI_SCALE_F32>(Qb + (long)z * 2048 * 1024, 1024,
                              Kb + (long)z * 2048 * 1024, 1024,
                              Sc, nullptr, (long)z * 2048 * 2048, 2048,
                              nullptr, nullptr, 1.0f / 128.0f, 16, tm, tn, As, Bs);
  }
}

// ========== counted-vmcnt 8-wave 128x128 GEMM (round-8, for 1-block/CU) ======
template <int EPI>
__device__ __forceinline__
void gemm_body(const u16* __restrict__ Ab, int lda,
               const u16* __restrict__ Bb, int ldb,
               void* __restrict__ Cv, void* __restrict__ Cv2, long coff, int ldc,
               const float* __restrict__ bias, const float* __restrict__ bias2,
               float scale, int kTiles, long tm, long tn,
               u16* As0, u16* As1, u16* Bs0, u16* Bs1) {
  const int tid = threadIdx.x, lane = tid & 63, w = tid >> 6;
  const int wm = w >> 2, wn = w & 3;      // wave grid 2x4
  const int rl = lane >> 3;
  const int sl = (lane & 7) ^ rl;
  const int fr = lane & 15, fq = lane >> 4;

  const u16* gA = Ab + (tm + w * 16 + rl) * (long)lda + sl * 8;
  const u16* gB = Bb + (tn + w * 16 + rl) * (long)ldb + sl * 8;

  f32x4 acc[4][2] = {};
  bf16x8 af[4][2], bfr[2][2];

#define STAGE(AsX, BsX, kt_)                                                    \
  {                                                                             \
    const int k0_ = (kt_) * 64;                                                 \
    __builtin_amdgcn_global_load_lds(GAS(gA + k0_),            LAS(AsX + w * 1024),       16, 0, 0); \
    __builtin_amdgcn_global_load_lds(GAS(gA + k0_ + 8 * lda),  LAS(AsX + w * 1024 + 512), 16, 0, 0); \
    __builtin_amdgcn_global_load_lds(GAS(gB + k0_),            LAS(BsX + w * 1024),       16, 0, 0); \
    __builtin_amdgcn_global_load_lds(GAS(gB + k0_ + 8 * ldb),  LAS(BsX + w * 1024 + 512), 16, 0, 0); \
  }

#define READF(AsX, BsX)                                                         \
  {                                                                             \
    _Pragma("unroll")                                                           \
    for (int mt = 0; mt < 4; ++mt)                                              \
      _Pragma("unroll")                                                         \
      for (int ks = 0; ks < 2; ++ks)                                            \
        af[mt][ks] = *(const bf16x8*)((AsX) + (wm * 64 + mt * 16 + fr) * 64 +   \
                                      ((ks * 4 + fq) ^ (fr & 7)) * 8);          \
    _Pragma("unroll")                                                           \
    for (int nt = 0; nt < 2; ++nt)                                              \
      _Pragma("unroll")                                                         \
      for (int ks = 0; ks < 2; ++ks)                                            \
        bfr[nt][ks] = *(const bf16x8*)((BsX) + (wn * 32 + nt * 16 + fr) * 64 +  \
                                       ((ks * 4 + fq) ^ (fr & 7)) * 8);         \
  }

#define MFMAS                                                                   \
  {                                                                             \
    __builtin_amdgcn_s_setprio(1);                                              \
    _Pragma("unroll")                                                           \
    for (int ks = 0; ks < 2; ++ks)                                              \
      _Pragma("unroll")                                                         \
      for (int mt = 0; mt < 4; ++mt)                                            \
        _Pragma("unroll")                                                       \
        for (int nt = 0; nt < 2; ++nt)                                          \
          acc[mt][nt] = __builtin_amdgcn_mfma_f32_16x16x32_bf16(af[mt][ks], bfr[nt][ks], acc[mt][nt], 0, 0, 0); \
    __builtin_amdgcn_s_setprio(0);                                              \
  }

#define LGKM0_SB do { asm volatile("s_waitcnt lgkmcnt(0)" ::: "memory");        \
                      __builtin_amdgcn_sched_barrier(0);                        \
                      asm volatile("s_barrier" ::: "memory"); } while (0)
#define VM_SB(n) do { asm volatile("s_waitcnt vmcnt(" #n ")" ::: "memory");     \
                      asm volatile("s_barrier" ::: "memory"); } while (0)

  STAGE(As0, Bs0, 0);
  STAGE(As1, Bs1, 1);
  VM_SB(4);

  for (int kt = 0; kt < kTiles; kt += 2) {
    READF(As0, Bs0);
    LGKM0_SB;
    if (kt + 2 < kTiles) STAGE(As0, Bs0, kt + 2);
    MFMAS;
    if (kt + 2 < kTiles) VM_SB(4); else VM_SB(0);
    READF(As1, Bs1);
    LGKM0_SB;
    if (kt + 3 < kTiles) STAGE(As1, Bs1, kt + 3);
    MFMAS;
    if (kt + 2 < kTiles) {
      if (kt + 3 < kTiles) VM_SB(4); else VM_SB(0);
    }
  }
#undef STAGE
#undef READF
#undef MFMAS
#undef LGKM0_SB
#undef VM_SB

  const int cr = (lane >> 4) * 4;
  const int cc = lane & 15;
#pragma unroll
  for (int mt = 0; mt < 4; ++mt) {
#pragma unroll
    for (int nt = 0; nt < 2; ++nt) {
#pragma unroll
      for (int r = 0; r < 4; ++r) {
        float v = acc[mt][nt][r];
        long gm = tm + wm * 64 + mt * 16 + cr + r;
        long gn = tn + wn * 32 + nt * 16 + cc;
        if constexpr (EPI == EPI_BIAS_COL_F32) {
          ((float*)Cv)[gm * (long)ldc + gn] = v + bias[gn];
        } else {  // EPI_RESHAPE_BF16
          long rr  = (gn >> 6) * 128 + (gm >> 4);
          long cc2 = ((gm & 15) << 6) + (gn & 63);
          ((u16*)Cv)[coff + rr * 1024 + cc2] = f2bf(v);
        }
      }
    }
  }
}

template <int EPI>
__global__ __launch_bounds__(512, 4)
void k_gemm(const u16* __restrict__ A, long sAz, int lda,
            const u16* __restrict__ Bt, long sBz, int ldb,
            void* __restrict__ Cv, long sCz, int ldc,
            const float* __restrict__ bias, float scale, int kTiles) {
  __shared__ __align__(16) u16 As[2][8192], Bs[2][8192];
  long tm = (long)blockIdx.x * 128, tn = (long)blockIdx.y * 128;
  gemm_body<EPI>(A + (long)blockIdx.z * sAz, lda, Bt + (long)blockIdx.z * sBz, ldb,
                 Cv, nullptr, (long)blockIdx.z * sCz, ldc, bias, nullptr,
                 scale, kTiles, tm, tn, As[0], As[1], Bs[0], Bs[1]);
}

// ---------------- row softmax: f32 [4096][2048] -> bf16 weights ----------------
__global__ __launch_bounds__(256) void softmax_k(const float* __restrict__ S,
                                                 u16* __restrict__ W) {
  const long row = blockIdx.x;
  const float* src = S + row * 2048;
  u16* dst = W + row * 2048;
  const int t = threadIdx.x, lane = t & 63, wid = t >> 6;

  const float4* sp = (const float4*)(src + t * 8);
  float4 a = sp[0], b = sp[1];
  float m = fmaxf(fmaxf(fmaxf(a.x, a.y), fmaxf(a.z, a.w)),
                  fmaxf(fmaxf(b.x, b.y), fmaxf(b.z, b.w)));
#pragma unroll
  for (int o = 32; o > 0; o >>= 1) m = fmaxf(m, __shfl_xor(m, o));
  __shared__ float redm[4], reds[4];
  if (lane == 0) redm[wid] = m;
  __syncthreads();
  m = fmaxf(fmaxf(redm[0], redm[1]), fmaxf(redm[2], redm[3]));

  float e[8];
  e[0] = __expf(a.x - m); e[1] = __expf(a.y - m);
  e[2] = __expf(a.z - m); e[3] = __expf(a.w - m);
  e[4] = __expf(b.x - m); e[5] = __expf(b.y - m);
  e[6] = __expf(b.z - m); e[7] = __expf(b.w - m);
  float s = ((e[0] + e[1]) + (e[2] + e[3])) + ((e[4] + e[5]) + (e[6] + e[7]));
#pragma unroll
  for (int o = 32; o > 0; o >>= 1) s += __shfl_xor(s, o);
  if (lane == 0) reds[wid] = s;
  __syncthreads();
  s = (reds[0] + reds[1]) + (reds[2] + reds[3]);
  float inv = 1.0f / s;

  uint4 o4;
  o4.x = pack2(e[0] * inv, e[1] * inv);
  o4.y = pack2(e[2] * inv, e[3] * inv);
  o4.z = pack2(e[4] * inv, e[5] * inv);
  o4.w = pack2(e[6] * inv, e[7] * inv);
  *(uint4*)(dst + t * 8) = o4;
}

// ---------------- launch ----------------
extern "C" void kernel_launch(void* const* d_in, const int* in_sizes, int n_in,
                              void* d_out, int out_size, void* d_ws, size_t ws_size,
                              hipStream_t stream) {
  const float* query = (const float*)d_in[0];
  const float* Wq = (const float*)d_in[1];
  const float* bq = (const float*)d_in[2];
  const float* Wk = (const float*)d_in[3];
  const float* bk = (const float*)d_in[4];
  const float* Wv = (const float*)d_in[5];
  const float* bv = (const float*)d_in[6];
  const float* Wo = (const float*)d_in[7];
  const float* bo = (const float*)d_in[8];
  float* out = (float*)d_out;

  char* ws = (char*)d_ws;
  u16*   Xb   = (u16*)(ws);                  // query bf16 [4096][1024]
  u16*   Wqkb = (u16*)(ws + 8388608);        // [2048][1024]
  u16*   Wvb  = (u16*)(ws + 12582912);
  u16*   Wob  = (u16*)(ws + 14680064);
  u16*   Qb   = (u16*)(ws + 16777216);       // [4096][1024]
  u16*   Kb   = (u16*)(ws + 25165824);       // [4096][1024]
  u16*   Vtb  = (u16*)(ws + 33554432);       // [1024][4096]
  u16*   Rb   = (u16*)(ws + 41943040);       // [2][2048][1024]
  float* Sc   = (float*)(ws + 50331648);     // [2][2048][2048] f32
  u16*   Wt   = (u16*)(ws + 83886080);       // [2][2048][2048] bf16

  cvt_all<<<4096, 256, 0, stream>>>(query, Wq, Wk, Wv, Wo, Xb, Wqkb, Wvb, Wob);

  // [Q|K] = X@[Wq;Wk]^T + bias  (512 tiles = 2/CU, 4-wave m97 body)
  k_qk<<<512, 256, 0, stream>>>(Xb, Wqkb, Qb, Kb, bq, bk);

  // Vt = Wv@X^T + bv  AND  scores = (Q@K^T)/128  (768 tiles = 3/CU, 4-wave)
  k_vsc<<<768, 256, 0, stream>>>(Xb, Wvb, Qb, Kb, Vtb, Sc, bv);

  softmax_k<<<4096, 256, 0, stream>>>(Sc, Wt);

  // AO = W@V per batch (K=2048), faithful-reshape epilogue (256 tiles, 8-wave)
  k_gemm<EPI_RESHAPE_BF16><<<dim3(16, 8, 2), 512, 0, stream>>>(
      Wt, 2048L * 2048, 2048, Vtb, 2048, 4096,
      Rb, 2048L * 1024, 1024, nullptr, 0.f, 32);

  // out = R@Wo^T + bo (256 tiles, 8-wave)
  k_gemm<EPI_BIAS_COL_F32><<<dim3(32, 8, 1), 512, 0, stream>>>(
      Rb, 0, 1024, Wob, 0, 1024, out, 0, 1024, bo, 0.f, 16);
}